// Round 4
// baseline (456.838 us; speedup 1.0000x reference)
//
#include <hip/hip_runtime.h>
#include <hip/hip_bf16.h>

// FastASTEncoder round 4: attn rewrite (XCD-local gather, fold-reduce softmax,
// SGPR gather bases) + GEMM double-buffered counted-vmcnt pipeline (T3 2-phase).
//
// Workspace (~92 MiB):
//   [0,32M)   p0/p1 fp32 partials [2][8192][512]  (overlaps qkvb bf16 [8192][1536])
//   [32,64M)  h1   bf16 [8192][2048]
//   [64,72M)  xb   bf16 [8192][512]
//   [72,80M)  cbuf bf16 [8192][512]
//   [80M+)    transposed bf16 weights

#define BB 16
#define NN 512
#define DMM 512
#define HH 8
#define DKK 64
#define RR 8
#define LL 2
#define DFFV 2048
#define PAR_HEADS 4
#define EPSV 1e-5f

typedef __bf16 bf16x8 __attribute__((ext_vector_type(8)));
typedef float f32x4 __attribute__((ext_vector_type(4)));

__device__ __forceinline__ unsigned short f2bf(float f) {
    unsigned u = __float_as_uint(f);
    u += 0x7fff + ((u >> 16) & 1);   // RNE
    return (unsigned short)(u >> 16);
}
__device__ __forceinline__ float bf2f(unsigned short u) {
    return __uint_as_float(((unsigned)u) << 16);
}

// ---------------- fused transpose for the four [512][512] weight sets ----------------
__global__ __launch_bounds__(256) void transpose_qkvo_kernel(
    const float* __restrict__ Wq, const float* __restrict__ Wk,
    const float* __restrict__ Wv, const float* __restrict__ Wo,
    unsigned short* __restrict__ wqkvT, unsigned short* __restrict__ woT)
{
    __shared__ float tile[32][33];
    int layer = blockIdx.z >> 2, which = blockIdx.z & 3;
    const float* s = (which == 0 ? Wq : which == 1 ? Wk : which == 2 ? Wv : Wo)
                     + (size_t)layer * DMM * DMM;
    unsigned short* d = (which < 3)
        ? wqkvT + (size_t)layer * 1536 * DMM + (size_t)which * DMM * DMM
        : woT + (size_t)layer * DMM * DMM;
    int k0 = blockIdx.y * 32, n0 = blockIdx.x * 32;
    int tx = threadIdx.x & 31, ty = threadIdx.x >> 5;
#pragma unroll
    for (int i = 0; i < 4; ++i)
        tile[ty + i * 8][tx] = s[(size_t)(k0 + ty + i * 8) * DMM + (n0 + tx)];
    __syncthreads();
#pragma unroll
    for (int i = 0; i < 4; ++i)
        d[(size_t)(n0 + ty + i * 8) * DMM + (k0 + tx)] = f2bf(tile[tx][ty + i * 8]);
}

// generic transpose [z][K][N] fp32 -> bf16 [N][K] (for W1, W2)
__global__ __launch_bounds__(256) void transpose_w_kernel(
    const float* __restrict__ src, unsigned short* __restrict__ dst,
    int K, int N, size_t zStride)
{
    __shared__ float tile[32][33];
    const float* s = src + (size_t)blockIdx.z * K * N;
    unsigned short* d = dst + (size_t)blockIdx.z * zStride;
    int k0 = blockIdx.y * 32, n0 = blockIdx.x * 32;
    int tx = threadIdx.x & 31, ty = threadIdx.x >> 5;
#pragma unroll
    for (int i = 0; i < 4; ++i)
        tile[ty + i * 8][tx] = s[(size_t)(k0 + ty + i * 8) * N + (n0 + tx)];
    __syncthreads();
#pragma unroll
    for (int i = 0; i < 4; ++i)
        d[(size_t)(n0 + ty + i * 8) * K + (k0 + tx)] = f2bf(tile[tx][ty + i * 8]);
}

// ---------------- x init ----------------
__global__ __launch_bounds__(256) void convert_x_kernel(
    const float* __restrict__ src, float* __restrict__ x, unsigned short* __restrict__ xb, int n4)
{
    int i = blockIdx.x * blockDim.x + threadIdx.x;
    int stride = gridDim.x * blockDim.x;
    for (; i < n4; i += stride) {
        float4 f = ((const float4*)src)[i];
        ((float4*)x)[i] = f;
        ushort4 u;
        u.x = f2bf(f.x); u.y = f2bf(f.y); u.z = f2bf(f.z); u.w = f2bf(f.w);
        ((ushort4*)xb)[i] = u;
    }
}

// ---------------- bf16 GEMM: C[M][N] = A[M][K] @ Bt[N][K]^T ----------------
// Tile 128x64, BK=64, 4 waves, double-buffered LDS with counted vmcnt (T3 2-phase):
// per iteration: issue next tile's 6 global_load_lds -> s_waitcnt vmcnt(6) ->
// s_barrier -> ds_read+MFMA -> s_barrier. Loads stay in flight across compute.
// LDS 8-slot XOR swizzle both-sides (rule #21). Split-K via blockIdx.z.
template<bool OUTBF, bool DORELU>
__global__ __launch_bounds__(256) void gemm_kernel(
    const unsigned short* __restrict__ A,   // [M][K] bf16
    const unsigned short* __restrict__ Bt,  // [N][K] bf16
    float* __restrict__ Cf,                 // fp32 out (if !OUTBF)
    unsigned short* __restrict__ Cb,        // bf16 out (if OUTBF)
    const float* __restrict__ bias,         // [N] or null
    int M, int N, int K, int kLen)
{
    constexpr int BM = 128, BN = 64, BK = 64;
    __shared__ __align__(16) unsigned short As[2][BM * BK];
    __shared__ __align__(16) unsigned short Bs[2][BN * BK];
    int tid = threadIdx.x, lane = tid & 63, w = tid >> 6;
    int wr = w >> 1, wc = w & 1;

    // XCD-bijective swizzle over (x,y); nwg % 8 == 0 for all our grids
    int gx = gridDim.x;
    int nwg = gx * gridDim.y;
    int flat = blockIdx.x + gx * blockIdx.y;
    int qq = nwg >> 3;
    int swz = (flat & 7) * qq + (flat >> 3);
    int bx = swz % gx, by = swz / gx;
    int mBase = by * BM, nBase = bx * BN;
    int kStart = blockIdx.z * kLen;

    const unsigned short* gA = A + (size_t)mBase * K;
    const unsigned short* gB = Bt + (size_t)nBase * K;

    f32x4 acc[4][2];
#pragma unroll
    for (int i = 0; i < 4; ++i)
#pragma unroll
        for (int j = 0; j < 2; ++j) acc[i][j] = (f32x4){0.f, 0.f, 0.f, 0.f};

    auto stage = [&](int buf, int k0) {
#pragma unroll
        for (int it = 0; it < 4; ++it) {
            int i = it * 256 + tid;
            int row = i >> 3, slot = i & 7;
            int gcol = (slot ^ (row & 7)) * 8;
            __builtin_amdgcn_global_load_lds(
                (const __attribute__((address_space(1))) void*)(gA + (size_t)row * K + k0 + gcol),
                (__attribute__((address_space(3))) void*)(As[buf] + i * 8), 16, 0, 0);
        }
#pragma unroll
        for (int it = 0; it < 2; ++it) {
            int i = it * 256 + tid;
            int row = i >> 3, slot = i & 7;
            int gcol = (slot ^ (row & 7)) * 8;
            __builtin_amdgcn_global_load_lds(
                (const __attribute__((address_space(1))) void*)(gB + (size_t)row * K + k0 + gcol),
                (__attribute__((address_space(3))) void*)(Bs[buf] + i * 8), 16, 0, 0);
        }
    };

    int nt = kLen / BK;
    stage(0, kStart);
    int cur = 0;
    for (int t = 0; t < nt; ++t) {
        if (t + 1 < nt) {
            stage(cur ^ 1, kStart + (t + 1) * BK);
            asm volatile("s_waitcnt vmcnt(6)" ::: "memory");   // cur's 6 done; next's in flight
        } else {
            asm volatile("s_waitcnt vmcnt(0)" ::: "memory");
        }
        __builtin_amdgcn_s_barrier();

        int rsel = lane & 15, g0 = lane >> 4;
        bf16x8 a[4][2], b[2][2];
#pragma unroll
        for (int m = 0; m < 4; ++m) {
            int row = wr * 64 + m * 16 + rsel;
#pragma unroll
            for (int ks = 0; ks < 2; ++ks) {
                int s = (g0 + ks * 4) ^ (row & 7);
                a[m][ks] = *(const bf16x8*)((const char*)As[cur] + row * 128 + s * 16);
            }
        }
#pragma unroll
        for (int n = 0; n < 2; ++n) {
            int row = wc * 32 + n * 16 + rsel;
#pragma unroll
            for (int ks = 0; ks < 2; ++ks) {
                int s = (g0 + ks * 4) ^ (row & 7);
                b[n][ks] = *(const bf16x8*)((const char*)Bs[cur] + row * 128 + s * 16);
            }
        }
#pragma unroll
        for (int m = 0; m < 4; ++m)
#pragma unroll
            for (int n = 0; n < 2; ++n)
#pragma unroll
                for (int ks = 0; ks < 2; ++ks)
                    acc[m][n] = __builtin_amdgcn_mfma_f32_16x16x32_bf16(a[m][ks], b[n][ks], acc[m][n], 0, 0, 0);
        __builtin_amdgcn_s_barrier();
        cur ^= 1;
    }

    // epilogue: C/D layout col=lane&15, row=(lane>>4)*4+j  [m89-verified]
    size_t zoff = (size_t)blockIdx.z * M * N;
    int rbase = (lane >> 4) * 4;
    int cloc = lane & 15;
#pragma unroll
    for (int m = 0; m < 4; ++m) {
#pragma unroll
        for (int n = 0; n < 2; ++n) {
            int col = nBase + wc * 32 + n * 16 + cloc;
            float bv = bias ? bias[col] : 0.0f;
#pragma unroll
            for (int j = 0; j < 4; ++j) {
                int row = mBase + wr * 64 + m * 16 + rbase + j;
                float val = acc[m][n][j] + bv;
                if (DORELU) val = fmaxf(val, 0.0f);
                if (OUTBF) Cb[zoff + (size_t)row * N + col] = f2bf(val);
                else       Cf[zoff + (size_t)row * N + col] = val;
            }
        }
    }
}

// ---------------- sparse relational attention, round-4 structure ----------------
// Grid 2048 blocks x 256. Block decode keeps each batch b on XCD b&7 so the k/v
// gather working set per XCD = 2 batches of qkv = 3 MB < 4 MB L2.
// Wave handles 8 consecutive n of one (b,h); lane = d.
// Edges loaded once per wave (lane = nl*8+r), broadcast via readlane -> SGPR bases.
// Score reduce: 3 fold steps (7 shfl) + 3 butterfly -> lane holds s_{lane&7};
// softmax within 8-lane groups (1 exp/lane); PV via 8 bpermute broadcasts of a_r.
__global__ __launch_bounds__(256) void attn_kernel(
    const unsigned short* __restrict__ qkv,
    const int* __restrict__ par, const int* __restrict__ bro,
    const float* __restrict__ relq, const float* __restrict__ relk,
    const float* __restrict__ relv, unsigned short* __restrict__ cb)
{
    int f = blockIdx.x;
    int xcd = f & 7;
    int j = f >> 3;                 // 0..255
    int b = xcd + 8 * (j & 1);
    int rem = j >> 1;               // 0..127
    int h = rem >> 4;               // 0..7
    int n0 = (rem & 15) * 32;
    int w = threadIdx.x >> 6;
    int lane = threadIdx.x & 63;
    int nw = n0 + w * 8;

    // rel tables for this head (lane = d), hoisted once per wave
    float rq[RR], rk[RR], rv[RR];
#pragma unroll
    for (int r = 0; r < RR; ++r) {
        rq[r] = relq[(h * RR + r) * DKK + lane];
        rk[r] = relk[(h * RR + r) * DKK + lane];
        rv[r] = relv[(h * RR + r) * DKK + lane];
    }
    const int* edges = (h < PAR_HEADS) ? par : bro;
    // all 64 edge indices for this wave's 8 n's: lane = nl*8 + r
    int e_all = edges[(b * RR + (lane & 7)) * NN + nw + (lane >> 3)];

    const unsigned short* qrow = qkv + (size_t)b * NN * 1536 + h * DKK;

#pragma unroll
    for (int nl = 0; nl < 8; ++nl) {
        int n = nw + nl;
        float qd = bf2f(qrow[(size_t)n * 1536 + lane]);
        float t[RR];
        int e[RR];
#pragma unroll
        for (int r = 0; r < RR; ++r) {
            int er = __builtin_amdgcn_readlane(e_all, nl * 8 + r);   // SGPR
            e[r] = er;
            float kd = bf2f(qkv[(size_t)(b * NN + er) * 1536 + DMM + h * DKK + lane]);
            t[r] = kd * (qd + rq[r]) + qd * rk[r];
        }
        // fold-reduce: 8 values over 64 lanes -> lane holds full sum for r = lane&7
        {
            bool hb = lane & 4;
#pragma unroll
            for (int rr = 0; rr < 4; ++rr) {
                float send = hb ? t[rr] : t[rr + 4];
                float keep = hb ? t[rr + 4] : t[rr];
                t[rr] = keep + __shfl_xor(send, 4, 64);
            }
        }
        {
            bool hb = lane & 2;
#pragma unroll
            for (int rr = 0; rr < 2; ++rr) {
                float send = hb ? t[rr] : t[rr + 2];
                float keep = hb ? t[rr + 2] : t[rr];
                t[rr] = keep + __shfl_xor(send, 2, 64);
            }
        }
        {
            bool hb = lane & 1;
            float send = hb ? t[0] : t[1];
            float keep = hb ? t[1] : t[0];
            t[0] = keep + __shfl_xor(send, 1, 64);
        }
        float s = t[0];
        s += __shfl_xor(s, 8, 64);
        s += __shfl_xor(s, 16, 64);
        s += __shfl_xor(s, 32, 64);
        s *= 0.125f;                       // 1/sqrt(64)
        // softmax over r within each 8-lane group (groups hold identical values)
        float mx = s;
        mx = fmaxf(mx, __shfl_xor(mx, 1, 64));
        mx = fmaxf(mx, __shfl_xor(mx, 2, 64));
        mx = fmaxf(mx, __shfl_xor(mx, 4, 64));
        float ee = __expf(s - mx);
        float den = ee;
        den += __shfl_xor(den, 1, 64);
        den += __shfl_xor(den, 2, 64);
        den += __shfl_xor(den, 4, 64);
        float a = ee / den;
        // PV: broadcast a_r from lane (lane&56)|r, accumulate over gathered v + rel_v
        float od = 0.f;
#pragma unroll
        for (int r = 0; r < RR; ++r) {
            float ar = __shfl(a, (lane & 56) | r, 64);
            float vd = bf2f(qkv[(size_t)(b * NN + e[r]) * 1536 + 2 * DMM + h * DKK + lane]);
            od = fmaf(ar, vd + rv[r], od);
        }
        cb[(size_t)(b * NN + n) * DMM + h * DKK + lane] = f2bf(od);
    }
}

// ---------------- residual(+partials+bias) + LayerNorm ----------------
__global__ __launch_bounds__(256) void ln_kernel(
    const float* __restrict__ xin, const float* __restrict__ add0,
    const float* __restrict__ add1, const float* __restrict__ bias,
    float* __restrict__ xout, unsigned short* __restrict__ xbout,
    const float* __restrict__ g, const float* __restrict__ bb)
{
    int row = blockIdx.x * 4 + (threadIdx.x >> 6);
    int lane = threadIdx.x & 63;
    const float* xr = xin + (size_t)row * DMM;
    const float* a0 = add0 ? add0 + (size_t)row * DMM : nullptr;
    const float* a1 = add1 ? add1 + (size_t)row * DMM : nullptr;
    float vals[8];
    float s = 0.f;
#pragma unroll
    for (int j = 0; j < 8; ++j) {
        int c = lane + j * 64;
        float t = xr[c];
        if (a0) t += a0[c];
        if (a1) t += a1[c];
        if (bias) t += bias[c];
        vals[j] = t;
        s += t;
    }
#pragma unroll
    for (int off = 32; off > 0; off >>= 1) s += __shfl_xor(s, off, 64);
    float mean = s * (1.0f / DMM);
    float s2 = 0.f;
#pragma unroll
    for (int j = 0; j < 8; ++j) { float d = vals[j] - mean; s2 += d * d; }
#pragma unroll
    for (int off = 32; off > 0; off >>= 1) s2 += __shfl_xor(s2, off, 64);
    float inv = rsqrtf(s2 * (1.0f / DMM) + EPSV);
#pragma unroll
    for (int j = 0; j < 8; ++j) {
        int c = lane + j * 64;
        float y = (vals[j] - mean) * inv * g[c] + bb[c];
        xout[(size_t)row * DMM + c] = y;
        if (xbout) xbout[(size_t)row * DMM + c] = f2bf(y);
    }
}

extern "C" void kernel_launch(void* const* d_in, const int* in_sizes, int n_in,
                              void* d_out, int out_size, void* d_ws, size_t ws_size,
                              hipStream_t stream)
{
    const float* src_emb = (const float*)d_in[0];
    const int*   par     = (const int*)d_in[1];
    const int*   bro     = (const int*)d_in[2];
    const float* rel_q   = (const float*)d_in[3];
    const float* rel_k   = (const float*)d_in[4];
    const float* rel_v   = (const float*)d_in[5];
    const float* Wq      = (const float*)d_in[6];
    const float* Wk      = (const float*)d_in[7];
    const float* Wv      = (const float*)d_in[8];
    const float* Wo      = (const float*)d_in[9];
    const float* ln1_g   = (const float*)d_in[10];
    const float* ln1_b   = (const float*)d_in[11];
    const float* W1      = (const float*)d_in[12];
    const float* b1      = (const float*)d_in[13];
    const float* W2      = (const float*)d_in[14];
    const float* b2      = (const float*)d_in[15];
    const float* ln2_g   = (const float*)d_in[16];
    const float* ln2_b   = (const float*)d_in[17];
    const float* normf_g = (const float*)d_in[18];
    const float* normf_b = (const float*)d_in[19];

    const size_t MB = 1024 * 1024;
    const int M = BB * NN;  // 8192
    char* ws = (char*)d_ws;
    float*          p    = (float*)(ws + 0 * MB);
    unsigned short* qkvb = (unsigned short*)(ws + 0 * MB);    // overlaps p (disjoint lifetime)
    unsigned short* h1   = (unsigned short*)(ws + 32 * MB);
    unsigned short* xb   = (unsigned short*)(ws + 64 * MB);
    unsigned short* cbuf = (unsigned short*)(ws + 72 * MB);
    unsigned short* wqkvT = (unsigned short*)(ws + 80 * MB);
    unsigned short* woT  = wqkvT + (size_t)LL * 1536 * DMM;
    unsigned short* w1T  = woT + (size_t)LL * DMM * DMM;
    unsigned short* w2T  = w1T + (size_t)LL * DMM * DFFV;
    float* p0 = p;
    float* p1 = p + (size_t)M * DMM;
    float* x = (float*)d_out;

    transpose_qkvo_kernel<<<dim3(16, 16, LL * 4), 256, 0, stream>>>(
        Wq, Wk, Wv, Wo, wqkvT, woT);
    transpose_w_kernel<<<dim3(DFFV / 32, DMM / 32, LL), 256, 0, stream>>>(
        W1, w1T, DMM, DFFV, (size_t)DMM * DFFV);
    transpose_w_kernel<<<dim3(DMM / 32, DFFV / 32, LL), 256, 0, stream>>>(
        W2, w2T, DFFV, DMM, (size_t)DMM * DFFV);

    convert_x_kernel<<<2048, 256, 0, stream>>>(src_emb, x, xb, M * DMM / 4);

    for (int l = 0; l < LL; ++l) {
        const unsigned short* wqkv_l = wqkvT + (size_t)l * 1536 * DMM;
        const unsigned short* wo_l = woT + (size_t)l * DMM * DMM;
        const unsigned short* w1_l = w1T + (size_t)l * DMM * DFFV;
        const unsigned short* w2_l = w2T + (size_t)l * DFFV * DMM;

        // fused QKV: [8192,512]@[512,1536] -> bf16 qkvb
        gemm_kernel<true, false><<<dim3(1536 / 64, M / 128, 1), 256, 0, stream>>>(
            xb, wqkv_l, nullptr, qkvb, nullptr, M, 1536, DMM, DMM);

        attn_kernel<<<2048, 256, 0, stream>>>(qkvb, par, bro, rel_q, rel_k, rel_v, cbuf);

        // Wo: split-K=2; partials summed in ln1
        gemm_kernel<false, false><<<dim3(512 / 64, M / 128, 2), 256, 0, stream>>>(
            cbuf, wo_l, p, nullptr, nullptr, M, DMM, DMM, DMM / 2);
        ln_kernel<<<M / 4, 256, 0, stream>>>(x, p0, p1, nullptr, x, xb,
                                             ln1_g + l * DMM, ln1_b + l * DMM);

        // W1: bias+relu, bf16 out
        gemm_kernel<true, true><<<dim3(DFFV / 64, M / 128, 1), 256, 0, stream>>>(
            xb, w1_l, nullptr, h1, b1 + l * DFFV, M, DFFV, DMM, DMM);
        // W2: split-K=2 (K=1024 each); b2 added in ln2
        gemm_kernel<false, false><<<dim3(512 / 64, M / 128, 2), 256, 0, stream>>>(
            h1, w2_l, p, nullptr, nullptr, M, DMM, DFFV, DFFV / 2);
        ln_kernel<<<M / 4, 256, 0, stream>>>(x, p0, p1, b2 + l * DMM, x, xb,
                                             ln2_g + l * DMM, ln2_b + l * DMM);
    }

    ln_kernel<<<M / 4, 256, 0, stream>>>(x, nullptr, nullptr, nullptr, x, nullptr,
                                         normf_g, normf_b);
}